// Round 2
// baseline (4625.656 us; speedup 1.0000x reference)
//
#include <hip/hip_runtime.h>
#include <stdint.h>

#define HW    480
#define KS    24
#define CH    3
#define HO    457            // 480-24+1
#define NPOS  (HO*HO)        // 208849
#define NP    400
#define PS    (CH*KS*KS)     // 1728
#define SIG   1e-6f

// ---------------- prep kernels ----------------

// Repack x_dec patches into Wp[p][c][kh][kw] contiguous (400 x 1728)
__global__ void repack_k(const float* __restrict__ x, float* __restrict__ Wp) {
    int t = blockIdx.x * 256 + threadIdx.x;
    if (t >= NP * PS) return;
    int p = t / PS, e = t - p * PS;
    int c = e / (KS * KS);
    int r = (e / KS) % KS;
    int w = e % KS;
    int pr = p / 20, pc = p - pr * 20;
    Wp[t] = x[c * HW * HW + (pr * KS + r) * HW + (pc * KS + w)];
}

// Per-patch mean and |den_x|
__global__ void stats_k(const float* __restrict__ Wp,
                        float* __restrict__ meanX, float* __restrict__ denXa) {
    __shared__ float shs[4], shs2[4];
    int p = blockIdx.x;
    float s = 0.f, s2 = 0.f;
    for (int e = threadIdx.x; e < PS; e += 256) {
        float v = Wp[p * PS + e];
        s += v; s2 += v * v;
    }
    for (int o = 32; o > 0; o >>= 1) { s += __shfl_down(s, o); s2 += __shfl_down(s2, o); }
    int lane = threadIdx.x & 63, wv = threadIdx.x >> 6;
    if (lane == 0) { shs[wv] = s; shs2[wv] = s2; }
    __syncthreads();
    if (threadIdx.x == 0) {
        float S = shs[0] + shs[1] + shs[2] + shs[3];
        float S2 = shs2[0] + shs2[1] + shs2[2] + shs2[3];
        float m = S / (float)PS;
        meanX[p] = m;
        denXa[p] = fabsf(S2 / (float)PS - m * m);
    }
}

// Vertical 24-row sums of y_dec (channels folded): cs/cs2 are (457 x 480)
__global__ void colsum_k(const float* __restrict__ y,
                         float* __restrict__ cs, float* __restrict__ cs2) {
    int t = blockIdx.x * 256 + threadIdx.x;
    if (t >= HO * HW) return;
    int i = t / HW, w = t - i * HW;
    float s = 0.f, s2 = 0.f;
    for (int c = 0; c < CH; c++) {
        const float* base = y + c * HW * HW + i * HW + w;
        for (int dh = 0; dh < KS; dh++) {
            float v = base[dh * HW];
            s += v; s2 += v * v;
        }
    }
    cs[t] = s; cs2[t] = s2;
}

// Horizontal 24-col sums -> sumY, |den_y| per position (457 x 457)
// den_y = s2/ps - (s/ps)^2   (Round-1 bug: had an extra *PS on the mean^2 term)
__global__ void window_k(const float* __restrict__ cs, const float* __restrict__ cs2,
                         float* __restrict__ sumY, float* __restrict__ denYa) {
    int t = blockIdx.x * 256 + threadIdx.x;
    if (t >= NPOS) return;
    int i = t / HO, j = t - i * HO;
    const float* r  = cs  + i * HW + j;
    const float* r2 = cs2 + i * HW + j;
    float s = 0.f, s2 = 0.f;
    for (int d = 0; d < KS; d++) { s += r[d]; s2 += r2[d]; }
    sumY[t] = s;
    float ips = 1.0f / (float)PS;
    denYa[t] = fabsf(s2 * ips - (s * ips) * (s * ips));
}

// ---------------- main correlation + argmax ----------------
// Block: 256 threads = 4 waves. 16 patches x 256 positions (row i, cols j0..j0+255).
// Wave g handles patches pbase+g*4..+3; thread position j = j0 + lane*4 + u (u<4).
__launch_bounds__(256)
__global__ void corr_k(const float* __restrict__ y, const float* __restrict__ Wp,
                       const float* __restrict__ meanX, const float* __restrict__ denXa,
                       const float* __restrict__ sumY, const float* __restrict__ denYa,
                       unsigned long long* __restrict__ best) {
    __shared__ __align__(16) float lds_y[284];
    __shared__ __align__(16) float lds_w[16 * 24];

    const int tid  = threadIdx.x;
    const int lane = tid & 63;
    const int g    = tid >> 6;
    const int i    = blockIdx.y;
    const int j0   = blockIdx.x ? (HO - 256) : 0;   // 0 or 201 (overlap recompute is idempotent)
    const int pbase = blockIdx.z * 16;

    float acc[4][4];
#pragma unroll
    for (int u = 0; u < 4; u++)
#pragma unroll
        for (int v = 0; v < 4; v++) acc[u][v] = 0.f;

    for (int c = 0; c < CH; c++) {
        for (int kh = 0; kh < KS; kh++) {
            __syncthreads();
            // stage y row segment [j0, j0+279)
            const float* yrow = y + c * HW * HW + (i + kh) * HW + j0;
            for (int e = tid; e < 279; e += 256) lds_y[e] = yrow[e];
            // stage 16 patch weight rows (24 each)
            for (int e = tid; e < 384; e += 256) {
                int pp = e / 24, kw = e - pp * 24;
                lds_w[e] = Wp[(pbase + pp) * PS + c * (KS * KS) + kh * KS + kw];
            }
            __syncthreads();

            // y values for this thread's 4 positions across kw=0..23: 28 floats
            float4 yv4[7];
            const float4* yp = (const float4*)&lds_y[lane * 4];
#pragma unroll
            for (int q = 0; q < 7; q++) yv4[q] = yp[q];
            const float* yv = (const float*)yv4;

            const float4* wq = (const float4*)(lds_w + g * 4 * 24);
#pragma unroll
            for (int kq = 0; kq < 6; kq++) {
                float4 wv[4];
#pragma unroll
                for (int v = 0; v < 4; v++) wv[v] = wq[v * 6 + kq];
#pragma unroll
                for (int r = 0; r < 4; r++) {
                    const int kw = kq * 4 + r;
#pragma unroll
                    for (int v = 0; v < 4; v++) {
                        float w = ((const float*)&wv[v])[r];
#pragma unroll
                        for (int u = 0; u < 4; u++)
                            acc[u][v] = fmaf(yv[u + kw], w, acc[u][v]);
                    }
                }
            }
        }
    }

    // epilogue: corr + packed argmax
    const int jb = j0 + lane * 4;
    float sY[4], dYa[4];
#pragma unroll
    for (int u = 0; u < 4; u++) {
        sY[u]  = sumY[i * HO + jb + u];
        dYa[u] = denYa[i * HO + jb + u];
    }
    const float invps = 1.0f / (float)PS;
#pragma unroll
    for (int v = 0; v < 4; v++) {
        int pv = pbase + g * 4 + v;
        float mX = meanX[pv], dXa = denXa[pv];
        unsigned long long bp = 0ull;
#pragma unroll
        for (int u = 0; u < 4; u++) {
            float corr = (2.0f * (acc[u][v] - mX * sY[u]) * invps + SIG)
                       / (dXa + dYa[u] + SIG);
            unsigned ub = __float_as_uint(corr);
            ub = (ub & 0x80000000u) ? ~ub : (ub | 0x80000000u);
            unsigned idx = (unsigned)(i * HO + jb + u);
            unsigned long long pk = ((unsigned long long)ub << 32) | (unsigned)(~idx);
            bp = pk > bp ? pk : bp;
        }
        // wave max-reduce (64 lanes)
#pragma unroll
        for (int o = 32; o > 0; o >>= 1) {
            unsigned long long other = __shfl_down(bp, o);
            bp = other > bp ? other : bp;
        }
        if (lane == 0) atomicMax(&best[pv], bp);
    }
}

// ---------------- gather ----------------
__global__ void gather_k(const float* __restrict__ y,
                         const unsigned long long* __restrict__ best,
                         float* __restrict__ out) {
    int p = blockIdx.x;
    unsigned idx = ~((unsigned)(best[p] & 0xFFFFFFFFull));
    int r = idx / HO, cc = idx - r * HO;
    int pr = p / 20, pc = p - pr * 20;
    for (int e = threadIdx.x; e < PS; e += 256) {
        int c = e / (KS * KS);
        int kh = (e / KS) % KS;
        int kw = e % KS;
        out[c * HW * HW + (pr * KS + kh) * HW + (pc * KS + kw)] =
            y[c * HW * HW + (r + kh) * HW + (cc + kw)];
    }
}

// ---------------- launch ----------------
extern "C" void kernel_launch(void* const* d_in, const int* in_sizes, int n_in,
                              void* d_out, int out_size, void* d_ws, size_t ws_size,
                              hipStream_t stream) {
    const float* x_dec = (const float*)d_in[0];
    const float* y_dec = (const float*)d_in[1];
    const float* y     = (const float*)d_in[2];
    float* out = (float*)d_out;

    char* ws = (char*)d_ws;
    size_t off = 0;
    auto carve = [&](size_t bytes) -> void* {
        void* p = ws + off;
        off += (bytes + 255) & ~(size_t)255;
        return p;
    };
    float* Wp    = (float*)carve((size_t)NP * PS * 4);   // 2.76 MB
    float* cs    = (float*)carve((size_t)HO * HW * 4);   // 877 KB
    float* cs2   = (float*)carve((size_t)HO * HW * 4);
    float* sumY  = (float*)carve((size_t)NPOS * 4);      // 835 KB
    float* denYa = (float*)carve((size_t)NPOS * 4);
    float* meanX = (float*)carve((size_t)NP * 4);
    float* denXa = (float*)carve((size_t)NP * 4);
    unsigned long long* best = (unsigned long long*)carve((size_t)NP * 8);

    hipMemsetAsync(best, 0, (size_t)NP * 8, stream);

    repack_k<<<(NP * PS + 255) / 256, 256, 0, stream>>>(x_dec, Wp);
    stats_k<<<NP, 256, 0, stream>>>(Wp, meanX, denXa);
    colsum_k<<<(HO * HW + 255) / 256, 256, 0, stream>>>(y_dec, cs, cs2);
    window_k<<<(NPOS + 255) / 256, 256, 0, stream>>>(cs, cs2, sumY, denYa);

    dim3 grid(2, HO, 25);
    corr_k<<<grid, 256, 0, stream>>>(y_dec, Wp, meanX, denXa, sumY, denYa, best);

    gather_k<<<NP, 256, 0, stream>>>(y, best, out);
}

// Round 3
// 2664.742 us; speedup vs baseline: 1.7359x; 1.7359x over previous
//
#include <hip/hip_runtime.h>
#include <stdint.h>

#define HW    480
#define KS    24
#define CH    3
#define HO    457            // 480-24+1
#define NPOS  (HO*HO)        // 208849
#define NP    400
#define PS    (CH*KS*KS)     // 1728
#define SIG   1e-6f
#define NKI   (CH*KS)        // 72 k-iterations (one per (c,kh) row)

typedef __attribute__((ext_vector_type(8))) short short8;
typedef __attribute__((ext_vector_type(4))) float float4v;
typedef unsigned int uint;
typedef unsigned short ushort;
typedef unsigned long long ull;

static __device__ __forceinline__ ushort f2bf(float v) {
    uint u = __float_as_uint(v);
    uint r = (u + 0x7fffu + ((u >> 16) & 1u)) >> 16;   // RNE
    return (ushort)r;
}
static __device__ __forceinline__ float bf2f(ushort h) {
    return __uint_as_float(((uint)h) << 16);
}

// ---------------- prep kernels ----------------

// Repack x_dec patches into Wp[p][c][kh][kw] contiguous (400 x 1728), fp32
__global__ void repack_k(const float* __restrict__ x, float* __restrict__ Wp) {
    int t = blockIdx.x * 256 + threadIdx.x;
    if (t >= NP * PS) return;
    int p = t / PS, e = t - p * PS;
    int c = e / (KS * KS);
    int r = (e / KS) % KS;
    int w = e % KS;
    int pr = p / 20, pc = p - pr * 20;
    Wp[t] = x[c * HW * HW + (pr * KS + r) * HW + (pc * KS + w)];
}

// Per-patch mean and |den_x|
__global__ void stats_k(const float* __restrict__ Wp,
                        float* __restrict__ meanX, float* __restrict__ denXa) {
    __shared__ float shs[4], shs2[4];
    int p = blockIdx.x;
    float s = 0.f, s2 = 0.f;
    for (int e = threadIdx.x; e < PS; e += 256) {
        float v = Wp[p * PS + e];
        s += v; s2 += v * v;
    }
    for (int o = 32; o > 0; o >>= 1) { s += __shfl_down(s, o); s2 += __shfl_down(s2, o); }
    int lane = threadIdx.x & 63, wv = threadIdx.x >> 6;
    if (lane == 0) { shs[wv] = s; shs2[wv] = s2; }
    __syncthreads();
    if (threadIdx.x == 0) {
        float S = shs[0] + shs[1] + shs[2] + shs[3];
        float S2 = shs2[0] + shs2[1] + shs2[2] + shs2[3];
        float m = S / (float)PS;
        meanX[p] = m;
        denXa[p] = fabsf(S2 / (float)PS - m * m);
    }
}

// y_dec -> interleaved bf16 planes: yhl[pix] = hi | (lo<<16)
__global__ void split_y_k(const float* __restrict__ y, uint* __restrict__ yhl) {
    int t = blockIdx.x * 256 + threadIdx.x;
    if (t >= CH * HW * HW) return;
    float v = y[t];
    ushort h = f2bf(v);
    ushort l = f2bf(v - bf2f(h));
    yhl[t] = (uint)h | ((uint)l << 16);
}

// Pack A fragments: layout frag f = ((pg*72 + kiter)*5 + mt)*4 + tt*2 + plane,
// 512 bf16 per frag, element (kwg,m,e) at kwg*128 + m*8 + e.
// A_t[p][k] = W[p][k - t] for (k-t) in [0,24), else 0.
__global__ void packA_k(const float* __restrict__ Wp, ushort* __restrict__ Ap) {
    int id = blockIdx.x * 256 + threadIdx.x;
    if (id >= 5 * NKI * 5 * 4 * 512) return;
    int within = id & 511;
    int e   = within & 7;
    int m   = (within >> 3) & 15;
    int kwg = within >> 7;
    int f = id >> 9;
    int plane = f & 1;
    int tt    = (f >> 1) & 1;
    int g2    = f >> 2;
    int mt    = g2 % 5;
    int g3    = g2 / 5;
    int kiter = g3 % NKI;
    int pg    = g3 / NKI;
    int kw = kwg * 8 + e - tt;
    float v = 0.f;
    if (kw >= 0 && kw < KS) {
        int p = pg * 80 + mt * 16 + m;
        v = Wp[p * PS + kiter * KS + kw];
    }
    ushort h = f2bf(v);
    ushort out = plane ? f2bf(v - bf2f(h)) : h;
    Ap[id] = out;
}

// Vertical 24-row sums of y_dec (channels folded): cs/cs2 are (457 x 480)
__global__ void colsum_k(const float* __restrict__ y,
                         float* __restrict__ cs, float* __restrict__ cs2) {
    int t = blockIdx.x * 256 + threadIdx.x;
    if (t >= HO * HW) return;
    int i = t / HW, w = t - i * HW;
    float s = 0.f, s2 = 0.f;
    for (int c = 0; c < CH; c++) {
        const float* base = y + c * HW * HW + i * HW + w;
        for (int dh = 0; dh < KS; dh++) {
            float v = base[dh * HW];
            s += v; s2 += v * v;
        }
    }
    cs[t] = s; cs2[t] = s2;
}

// Horizontal 24-col sums -> sumY, |den_y| per position (457 x 457)
__global__ void window_k(const float* __restrict__ cs, const float* __restrict__ cs2,
                         float* __restrict__ sumY, float* __restrict__ denYa) {
    int t = blockIdx.x * 256 + threadIdx.x;
    if (t >= NPOS) return;
    int i = t / HO, j = t - i * HO;
    const float* r  = cs  + i * HW + j;
    const float* r2 = cs2 + i * HW + j;
    float s = 0.f, s2 = 0.f;
    for (int d = 0; d < KS; d++) { s += r[d]; s2 += r2[d]; }
    sumY[t] = s;
    float ips = 1.0f / (float)PS;
    denYa[t] = fabsf(s2 * ips - (s * ips) * (s * ips));
}

// ---------------- main MFMA correlation + argmax ----------------
// grid(4=jtile, 457=i, 5=pg). Block: 256 thr = 4 waves.
// Block tile: 80 patches (pg*80..+79) x 128 positions (j0..j0+127).
// Wave g: 32 positions j = j0 + 32g + 2n + t  (n=0..15 = MFMA col, t=0..1 absorbed
// into pre-shifted A copies). K-loop: 72 (c,kh) rows, kw padded 24->32.
__launch_bounds__(256, 3)
__global__ void corr_mfma_k(const uint* __restrict__ yhl, const ushort* __restrict__ Ap,
                            const float* __restrict__ meanX, const float* __restrict__ denXa,
                            const float* __restrict__ sumY, const float* __restrict__ denYa,
                            ull* __restrict__ best) {
    __shared__ ushort Bl[NKI][2][160];   // 46080 B: bf16 hi/lo rows

    const int tid  = threadIdx.x;
    const int lane = tid & 63;
    const int g    = tid >> 6;
    const int n    = lane & 15;        // MFMA column (position sub-index)
    const int kwg  = lane >> 4;        // k-group of 8
    const int i    = blockIdx.y;
    const int pg   = blockIdx.z;
    static const int j0tab[4] = {0, 120, 240, 336};
    const int j0 = j0tab[blockIdx.x];

    // ---- stage 72 rows x 160 cols, hi+lo, one barrier ----
    for (int it = tid; it < NKI * 40; it += 256) {
        int r  = it / 40;
        int cg = it - r * 40;            // 4-col group
        int gcol = j0 + cg * 4;
        int c = r / KS, kh = r - c * KS;
        uint4 u = make_uint4(0, 0, 0, 0);
        if (gcol < HW)  // 480 % 4 == 0, j0 % 4 == 0 -> whole group in/out together
            u = *(const uint4*)(yhl + c * HW * HW + (i + kh) * HW + gcol);
        ushort4 h4, l4;
        h4.x = (ushort)(u.x & 0xffff); l4.x = (ushort)(u.x >> 16);
        h4.y = (ushort)(u.y & 0xffff); l4.y = (ushort)(u.y >> 16);
        h4.z = (ushort)(u.z & 0xffff); l4.z = (ushort)(u.z >> 16);
        h4.w = (ushort)(u.w & 0xffff); l4.w = (ushort)(u.w >> 16);
        *(ushort4*)&Bl[r][0][cg * 4] = h4;
        *(ushort4*)&Bl[r][1][cg * 4] = l4;
    }
    __syncthreads();

    float4v acc[5][2];
#pragma unroll
    for (int mt = 0; mt < 5; mt++)
#pragma unroll
        for (int tt = 0; tt < 2; tt++) acc[mt][tt] = (float4v)0.f;

    const int bidx = 32 * g + 2 * n + 8 * kwg;   // even -> uint-aligned

    for (int ki = 0; ki < NKI; ki++) {
        // B fragments (shared across all mt and both t)
        short8 bh, bl;
        {
            const uint* ph = (const uint*)&Bl[ki][0][bidx];
            const uint* pl = (const uint*)&Bl[ki][1][bidx];
            uint* bhp = (uint*)&bh; uint* blp = (uint*)&bl;
#pragma unroll
            for (int q = 0; q < 4; q++) { bhp[q] = ph[q]; blp[q] = pl[q]; }
        }
        const ushort* fb = Ap + ((((size_t)(pg * NKI + ki) * 5) * 4) << 9) + lane * 8;
#pragma unroll
        for (int mt = 0; mt < 5; mt++) {
            const ushort* fm = fb + ((size_t)mt << 11);   // mt*4 frags * 512
            short8 a0h = *(const short8*)(fm);
            short8 a0l = *(const short8*)(fm + 512);
            short8 a1h = *(const short8*)(fm + 1024);
            short8 a1l = *(const short8*)(fm + 1536);
            acc[mt][0] = __builtin_amdgcn_mfma_f32_16x16x32_bf16(a0h, bh, acc[mt][0], 0, 0, 0);
            acc[mt][0] = __builtin_amdgcn_mfma_f32_16x16x32_bf16(a0h, bl, acc[mt][0], 0, 0, 0);
            acc[mt][0] = __builtin_amdgcn_mfma_f32_16x16x32_bf16(a0l, bh, acc[mt][0], 0, 0, 0);
            acc[mt][1] = __builtin_amdgcn_mfma_f32_16x16x32_bf16(a1h, bh, acc[mt][1], 0, 0, 0);
            acc[mt][1] = __builtin_amdgcn_mfma_f32_16x16x32_bf16(a1h, bl, acc[mt][1], 0, 0, 0);
            acc[mt][1] = __builtin_amdgcn_mfma_f32_16x16x32_bf16(a1l, bh, acc[mt][1], 0, 0, 0);
        }
    }

    // ---- epilogue: corr + packed argmax ----
    const int jb = j0 + 32 * g;
    const float invps = 1.0f / (float)PS;
    float sY[2], dYa[2];
#pragma unroll
    for (int tt = 0; tt < 2; tt++) {
        int j = jb + 2 * n + tt;
        int jc = j <= (HO - 1) ? j : (HO - 1);
        sY[tt]  = sumY[i * HO + jc];
        dYa[tt] = denYa[i * HO + jc];
    }
#pragma unroll
    for (int mt = 0; mt < 5; mt++) {
#pragma unroll
        for (int r = 0; r < 4; r++) {
            int p = pg * 80 + mt * 16 + kwg * 4 + r;
            float mX = meanX[p], dXa = denXa[p];
            ull bp = 0ull;
#pragma unroll
            for (int tt = 0; tt < 2; tt++) {
                int j = jb + 2 * n + tt;
                if (j <= HO - 1) {
                    float corr = (2.0f * (acc[mt][tt][r] - mX * sY[tt]) * invps + SIG)
                               / (dXa + dYa[tt] + SIG);
                    uint ub = __float_as_uint(corr);
                    ub = (ub & 0x80000000u) ? ~ub : (ub | 0x80000000u);
                    uint idx = (uint)(i * HO + j);
                    ull pk = ((ull)ub << 32) | (uint)(~idx);
                    bp = pk > bp ? pk : bp;
                }
            }
            // reduce across the 16 lanes (n) holding this patch
#pragma unroll
            for (int o = 1; o < 16; o <<= 1) {
                ull other = __shfl_xor(bp, o);
                bp = other > bp ? other : bp;
            }
            if (n == 0) atomicMax(&best[p], bp);
        }
    }
}

// ---------------- gather ----------------
__global__ void gather_k(const float* __restrict__ y,
                         const ull* __restrict__ best,
                         float* __restrict__ out) {
    int p = blockIdx.x;
    uint idx = ~((uint)(best[p] & 0xFFFFFFFFull));
    int r = idx / HO, cc = idx - r * HO;
    int pr = p / 20, pc = p - pr * 20;
    for (int e = threadIdx.x; e < PS; e += 256) {
        int c = e / (KS * KS);
        int kh = (e / KS) % KS;
        int kw = e % KS;
        out[c * HW * HW + (pr * KS + kh) * HW + (pc * KS + kw)] =
            y[c * HW * HW + (r + kh) * HW + (cc + kw)];
    }
}

// ---------------- launch ----------------
extern "C" void kernel_launch(void* const* d_in, const int* in_sizes, int n_in,
                              void* d_out, int out_size, void* d_ws, size_t ws_size,
                              hipStream_t stream) {
    const float* x_dec = (const float*)d_in[0];
    const float* y_dec = (const float*)d_in[1];
    const float* y     = (const float*)d_in[2];
    float* out = (float*)d_out;

    char* ws = (char*)d_ws;
    size_t off = 0;
    auto carve = [&](size_t bytes) -> void* {
        void* p = ws + off;
        off += (bytes + 255) & ~(size_t)255;
        return p;
    };
    float* Wp    = (float*)carve((size_t)NP * PS * 4);          // 2.76 MB
    uint*  yhl   = (uint*)carve((size_t)CH * HW * HW * 4);      // 2.76 MB
    ushort* Ap   = (ushort*)carve((size_t)5 * NKI * 5 * 4 * 512 * 2); // 7.37 MB
    float* cs    = (float*)carve((size_t)HO * HW * 4);
    float* cs2   = (float*)carve((size_t)HO * HW * 4);
    float* sumY  = (float*)carve((size_t)NPOS * 4);
    float* denYa = (float*)carve((size_t)NPOS * 4);
    float* meanX = (float*)carve((size_t)NP * 4);
    float* denXa = (float*)carve((size_t)NP * 4);
    ull*   best  = (ull*)carve((size_t)NP * 8);

    hipMemsetAsync(best, 0, (size_t)NP * 8, stream);

    repack_k<<<(NP * PS + 255) / 256, 256, 0, stream>>>(x_dec, Wp);
    stats_k<<<NP, 256, 0, stream>>>(Wp, meanX, denXa);
    split_y_k<<<(CH * HW * HW + 255) / 256, 256, 0, stream>>>(y_dec, yhl);
    packA_k<<<(5 * NKI * 5 * 4 * 512 + 255) / 256, 256, 0, stream>>>(Wp, Ap);
    colsum_k<<<(HO * HW + 255) / 256, 256, 0, stream>>>(y_dec, cs, cs2);
    window_k<<<(NPOS + 255) / 256, 256, 0, stream>>>(cs, cs2, sumY, denYa);

    dim3 grid(4, HO, 5);   // pg slowest -> per-XCD L2 holds one pg's A slice
    corr_mfma_k<<<grid, 256, 0, stream>>>(yhl, Ap, meanX, denXa, sumY, denYa, best);

    gather_k<<<NP, 256, 0, stream>>>(y, best, out);
}

// Round 4
// 1218.570 us; speedup vs baseline: 3.7960x; 2.1868x over previous
//
#include <hip/hip_runtime.h>
#include <stdint.h>

#define HW    480
#define KS    24
#define CH    3
#define HO    457            // 480-24+1
#define NPOS  (HO*HO)        // 208849
#define NP    400
#define PS    (CH*KS*KS)     // 1728
#define SIG   1e-6f
#define NKI   (CH*KS)        // 72 k-iterations (one per (c,kh) row)
#define NMT   14             // 32-patch MFMA tiles (448 padded patches)
#define NPG   7              // blocks of 2 mt (64 patches)

typedef __attribute__((ext_vector_type(8))) short short8;
typedef __attribute__((ext_vector_type(16))) float float16v;
typedef unsigned int uint;
typedef unsigned short ushort;
typedef unsigned long long ull;

static __device__ __forceinline__ ushort f2bf(float v) {
    uint u = __float_as_uint(v);
    uint r = (u + 0x7fffu + ((u >> 16) & 1u)) >> 16;   // RNE
    return (ushort)r;
}
static __device__ __forceinline__ float bf2f(ushort h) {
    return __uint_as_float(((uint)h) << 16);
}

// ---------------- prep kernels ----------------

// Repack x_dec patches into Wp[p][c][kh][kw] contiguous (400 x 1728), fp32
__global__ void repack_k(const float* __restrict__ x, float* __restrict__ Wp) {
    int t = blockIdx.x * 256 + threadIdx.x;
    if (t >= NP * PS) return;
    int p = t / PS, e = t - p * PS;
    int c = e / (KS * KS);
    int r = (e / KS) % KS;
    int w = e % KS;
    int pr = p / 20, pc = p - pr * 20;
    Wp[t] = x[c * HW * HW + (pr * KS + r) * HW + (pc * KS + w)];
}

// Per-patch mean and |den_x|
__global__ void stats_k(const float* __restrict__ Wp,
                        float* __restrict__ meanX, float* __restrict__ denXa) {
    __shared__ float shs[4], shs2[4];
    int p = blockIdx.x;
    float s = 0.f, s2 = 0.f;
    for (int e = threadIdx.x; e < PS; e += 256) {
        float v = Wp[p * PS + e];
        s += v; s2 += v * v;
    }
    for (int o = 32; o > 0; o >>= 1) { s += __shfl_down(s, o); s2 += __shfl_down(s2, o); }
    int lane = threadIdx.x & 63, wv = threadIdx.x >> 6;
    if (lane == 0) { shs[wv] = s; shs2[wv] = s2; }
    __syncthreads();
    if (threadIdx.x == 0) {
        float S = shs[0] + shs[1] + shs[2] + shs[3];
        float S2 = shs2[0] + shs2[1] + shs2[2] + shs2[3];
        float m = S / (float)PS;
        meanX[p] = m;
        denXa[p] = fabsf(S2 / (float)PS - m * m);
    }
}

// y_dec -> interleaved bf16 planes: yhl[pix] = hi | (lo<<16)
__global__ void split_y_k(const float* __restrict__ y, uint* __restrict__ yhl) {
    int t = blockIdx.x * 256 + threadIdx.x;
    if (t >= CH * HW * HW) return;
    float v = y[t];
    ushort h = f2bf(v);
    ushort l = f2bf(v - bf2f(h));
    yhl[t] = (uint)h | ((uint)l << 16);
}

// Pack A fragments for 32x32x16: frag f = (mtg*72 + ki)*8 + (t*4 + pl*2 + ks)
// 512 bf16 per frag, element (lane,e) at lane*8 + e.
// A[m][k]: m = lane&31, k = (lane>>5)*8 + e  (k in [0,16) of kstep ks)
// padded kw' = ks*16 + k; real kw = kw' - t; zero outside [0,24) or p>=400.
__global__ void packA_k(const float* __restrict__ Wp, ushort* __restrict__ Ap) {
    int id = blockIdx.x * 256 + threadIdx.x;
    if (id >= NMT * NKI * 8 * 512) return;
    int e  = id & 7;
    int L  = (id >> 3) & 63;
    int f  = id >> 9;
    int ks = f & 1;
    int pl = (f >> 1) & 1;
    int t  = (f >> 2) & 1;
    int rest = f >> 3;
    int ki  = rest % NKI;
    int mtg = rest / NKI;
    int m = L & 31, kha = L >> 5;
    int kwp = ks * 16 + kha * 8 + e;
    int kw = kwp - t;
    int p = mtg * 32 + m;
    float v = 0.f;
    if (p < NP && kw >= 0 && kw < KS)
        v = Wp[p * PS + ki * KS + kw];
    ushort h = f2bf(v);
    Ap[id] = pl ? f2bf(v - bf2f(h)) : h;
}

// Vertical 24-row sums of y_dec (channels folded): cs/cs2 are (457 x 480)
__global__ void colsum_k(const float* __restrict__ y,
                         float* __restrict__ cs, float* __restrict__ cs2) {
    int t = blockIdx.x * 256 + threadIdx.x;
    if (t >= HO * HW) return;
    int i = t / HW, w = t - i * HW;
    float s = 0.f, s2 = 0.f;
    for (int c = 0; c < CH; c++) {
        const float* base = y + c * HW * HW + i * HW + w;
        for (int dh = 0; dh < KS; dh++) {
            float v = base[dh * HW];
            s += v; s2 += v * v;
        }
    }
    cs[t] = s; cs2[t] = s2;
}

// Horizontal 24-col sums -> sumY, |den_y| per position (457 x 457)
__global__ void window_k(const float* __restrict__ cs, const float* __restrict__ cs2,
                         float* __restrict__ sumY, float* __restrict__ denYa) {
    int t = blockIdx.x * 256 + threadIdx.x;
    if (t >= NPOS) return;
    int i = t / HO, j = t - i * HO;
    const float* r  = cs  + i * HW + j;
    const float* r2 = cs2 + i * HW + j;
    float s = 0.f, s2 = 0.f;
    for (int d = 0; d < KS; d++) { s += r[d]; s2 += r2[d]; }
    sumY[t] = s;
    float ips = 1.0f / (float)PS;
    denYa[t] = fabsf(s2 * ips - (s * ips) * (s * ips));
}

// ---------------- main 32x32x16 MFMA correlation + argmax ----------------
// grid(2=jt, 229=row-pair, 7=pg). Block: 256 thr = 4 waves = 2 mt x 2 col-halves.
// Wave: 32 patches x 256 positions = 2 i-rows x 2 s-groups x 64 (T=2: j=2n+t).
// K-loop: per channel stage 25 y-rows x 288 cols (hi/lo bf16) in LDS, then 24 kh.
__launch_bounds__(256, 2)
__global__ void corr32_k(const uint* __restrict__ yhl, const ushort* __restrict__ Ap,
                         const float* __restrict__ meanX, const float* __restrict__ denXa,
                         const float* __restrict__ sumY, const float* __restrict__ denYa,
                         ull* __restrict__ best) {
    __shared__ ushort Bh[25 * 288];
    __shared__ ushort Bl[25 * 288];

    const int tid  = threadIdx.x;
    const int lane = tid & 63;
    const int g    = tid >> 6;
    const int n    = lane & 31;     // MFMA column (position sub-index)
    const int kha  = lane >> 5;     // k-half / C-row-half selector
    const int sh   = g & 1;         // col-half of block
    const int mtw  = g >> 1;        // mt within block
    const int j0   = blockIdx.x ? 204 : 0;   // 4-aligned; jt1 cols 204..459 (j>=457 masked)
    const int i0   = blockIdx.y * 2;
    const int pg   = blockIdx.z;
    const int mtg  = pg * 2 + mtw;
    const int jb   = j0 + 128 * sh;
    const bool ri1ok = (i0 + 1) < HO;

    float16v acc[2][2][2];   // [t][ri][s]
#pragma unroll
    for (int t = 0; t < 2; t++)
#pragma unroll
        for (int ri = 0; ri < 2; ri++)
#pragma unroll
            for (int s = 0; s < 2; s++) acc[t][ri][s] = (float16v)0.f;

    for (int c = 0; c < CH; c++) {
        __syncthreads();   // previous chunk fully consumed
        // stage 25 rows x 288 cols (uint4 granules, 72 per row)
        for (int it = tid; it < 25 * 72; it += 256) {
            int d  = it / 72;
            int c4 = (it - d * 72) * 4;
            int yr = i0 + d;
            int gj = j0 + c4;
            uint4 u = make_uint4(0, 0, 0, 0);
            if (yr < HW) {
                const uint* q = yhl + c * HW * HW + yr * HW;
                if (gj + 3 < HW) u = *(const uint4*)(q + gj);   // 16B-aligned (j0%4==0)
                else {
                    if (gj + 0 < HW) u.x = q[gj + 0];
                    if (gj + 1 < HW) u.y = q[gj + 1];
                    if (gj + 2 < HW) u.z = q[gj + 2];
                }
            }
            ushort4 h4, l4;
            h4.x = (ushort)(u.x & 0xffff); l4.x = (ushort)(u.x >> 16);
            h4.y = (ushort)(u.y & 0xffff); l4.y = (ushort)(u.y >> 16);
            h4.z = (ushort)(u.z & 0xffff); l4.z = (ushort)(u.z >> 16);
            h4.w = (ushort)(u.w & 0xffff); l4.w = (ushort)(u.w >> 16);
            *(ushort4*)&Bh[d * 288 + c4] = h4;
            *(ushort4*)&Bl[d * 288 + c4] = l4;
        }
        __syncthreads();

        for (int kh = 0; kh < KS; kh++) {
            const int ki = c * KS + kh;
            const ushort* fb = Ap + (((size_t)(mtg * NKI + ki)) << 12) + lane * 8;
            short8 af[2][2][2];   // [t][pl][ks]
#pragma unroll
            for (int t = 0; t < 2; t++)
#pragma unroll
                for (int pl = 0; pl < 2; pl++)
#pragma unroll
                    for (int ks = 0; ks < 2; ks++)
                        af[t][pl][ks] = *(const short8*)(fb + (((t << 2) | (pl << 1) | ks) << 9));

#pragma unroll
            for (int ks = 0; ks < 2; ks++) {
#pragma unroll
                for (int ri = 0; ri < 2; ri++) {
                    const int d = kh + ri;
#pragma unroll
                    for (int s = 0; s < 2; s++) {
                        const int colb = 128 * sh + 64 * s + 16 * ks + 8 * kha + 2 * n;
                        const uint* ph = (const uint*)&Bh[d * 288 + colb];
                        const uint* pq = (const uint*)&Bl[d * 288 + colb];
                        union { uint u[4]; short8 v; } bh, bl;
#pragma unroll
                        for (int q = 0; q < 4; q++) { bh.u[q] = ph[q]; bl.u[q] = pq[q]; }
#pragma unroll
                        for (int t = 0; t < 2; t++) {
                            acc[t][ri][s] = __builtin_amdgcn_mfma_f32_32x32x16_bf16(af[t][0][ks], bh.v, acc[t][ri][s], 0, 0, 0);
                            acc[t][ri][s] = __builtin_amdgcn_mfma_f32_32x32x16_bf16(af[t][0][ks], bl.v, acc[t][ri][s], 0, 0, 0);
                            acc[t][ri][s] = __builtin_amdgcn_mfma_f32_32x32x16_bf16(af[t][1][ks], bh.v, acc[t][ri][s], 0, 0, 0);
                        }
                    }
                }
            }
        }
    }

    // ---- epilogue: corr + packed argmax ----
    const float invps = 1.0f / (float)PS;
    const int pbase = mtg * 32;
    float mXv[16], dXv[16];
#pragma unroll
    for (int r = 0; r < 16; r++) {
        int p = pbase + (r & 3) + 8 * (r >> 2) + 4 * kha;
        bool ok = p < NP;
        mXv[r] = ok ? meanX[p] : 0.f;
        dXv[r] = ok ? denXa[p] : 0.f;
    }
    float sYv[2][2][2], dYv[2][2][2];
#pragma unroll
    for (int ri = 0; ri < 2; ri++) {
        bool iok = (ri == 0) || ri1ok;
        int ib = (i0 + ri) * HO;
#pragma unroll
        for (int s = 0; s < 2; s++)
#pragma unroll
            for (int t = 0; t < 2; t++) {
                int j = jb + 64 * s + 2 * n + t;
                bool ok = iok && (j < HO);
                sYv[ri][s][t] = ok ? sumY[ib + j] : 0.f;
                dYv[ri][s][t] = ok ? denYa[ib + j] : 0.f;
            }
    }
#pragma unroll
    for (int r = 0; r < 16; r++) {
        ull bp = 0ull;
#pragma unroll
        for (int ri = 0; ri < 2; ri++) {
            if (ri == 1 && !ri1ok) continue;
#pragma unroll
            for (int s = 0; s < 2; s++)
#pragma unroll
                for (int t = 0; t < 2; t++) {
                    int j = jb + 64 * s + 2 * n + t;
                    if (j < HO) {
                        float xy = acc[t][ri][s][r];
                        float corr = (2.0f * (xy - mXv[r] * sYv[ri][s][t]) * invps + SIG)
                                   / (dXv[r] + dYv[ri][s][t] + SIG);
                        uint ub = __float_as_uint(corr);
                        ub = (ub & 0x80000000u) ? ~ub : (ub | 0x80000000u);
                        uint idx = (uint)((i0 + ri) * HO + j);
                        ull pk = ((ull)ub << 32) | (uint)(~idx);
                        bp = pk > bp ? pk : bp;
                    }
                }
        }
        // reduce across the 32 lanes (cols) of this half
#pragma unroll
        for (int o = 1; o < 32; o <<= 1) {
            ull other = __shfl_xor(bp, o);
            bp = other > bp ? other : bp;
        }
        if (n == 0) {
            int p = pbase + (r & 3) + 8 * (r >> 2) + 4 * kha;
            if (p < NP) atomicMax(&best[p], bp);
        }
    }
}

// ---------------- gather ----------------
__global__ void gather_k(const float* __restrict__ y,
                         const ull* __restrict__ best,
                         float* __restrict__ out) {
    int p = blockIdx.x;
    uint idx = ~((uint)(best[p] & 0xFFFFFFFFull));
    int r = idx / HO, cc = idx - r * HO;
    int pr = p / 20, pc = p - pr * 20;
    for (int e = threadIdx.x; e < PS; e += 256) {
        int c = e / (KS * KS);
        int kh = (e / KS) % KS;
        int kw = e % KS;
        out[c * HW * HW + (pr * KS + kh) * HW + (pc * KS + kw)] =
            y[c * HW * HW + (r + kh) * HW + (cc + kw)];
    }
}

// ---------------- launch ----------------
extern "C" void kernel_launch(void* const* d_in, const int* in_sizes, int n_in,
                              void* d_out, int out_size, void* d_ws, size_t ws_size,
                              hipStream_t stream) {
    const float* x_dec = (const float*)d_in[0];
    const float* y_dec = (const float*)d_in[1];
    const float* y     = (const float*)d_in[2];
    float* out = (float*)d_out;

    char* ws = (char*)d_ws;
    size_t off = 0;
    auto carve = [&](size_t bytes) -> void* {
        void* p = ws + off;
        off += (bytes + 255) & ~(size_t)255;
        return p;
    };
    float* Wp    = (float*)carve((size_t)NP * PS * 4);            // 2.76 MB
    uint*  yhl   = (uint*)carve((size_t)CH * HW * HW * 4);        // 2.76 MB
    ushort* Ap   = (ushort*)carve((size_t)NMT * NKI * 8 * 512 * 2); // 8.26 MB
    float* cs    = (float*)carve((size_t)HO * HW * 4);
    float* cs2   = (float*)carve((size_t)HO * HW * 4);
    float* sumY  = (float*)carve((size_t)NPOS * 4);
    float* denYa = (float*)carve((size_t)NPOS * 4);
    float* meanX = (float*)carve((size_t)NP * 4);
    float* denXa = (float*)carve((size_t)NP * 4);
    ull*   best  = (ull*)carve((size_t)NP * 8);

    hipMemsetAsync(best, 0, (size_t)NP * 8, stream);

    repack_k<<<(NP * PS + 255) / 256, 256, 0, stream>>>(x_dec, Wp);
    stats_k<<<NP, 256, 0, stream>>>(Wp, meanX, denXa);
    split_y_k<<<(CH * HW * HW + 255) / 256, 256, 0, stream>>>(y_dec, yhl);
    packA_k<<<(NMT * NKI * 8 * 512 + 255) / 256, 256, 0, stream>>>(Wp, Ap);
    colsum_k<<<(HO * HW + 255) / 256, 256, 0, stream>>>(y_dec, cs, cs2);
    window_k<<<(NPOS + 255) / 256, 256, 0, stream>>>(cs, cs2, sumY, denYa);

    dim3 grid(2, 229, NPG);
    corr32_k<<<grid, 256, 0, stream>>>(yhl, Ap, meanX, denXa, sumY, denYa, best);

    gather_k<<<NP, 256, 0, stream>>>(y, best, out);
}